// Round 8
// baseline (480.009 us; speedup 1.0000x reference)
//
#include <hip/hip_runtime.h>
#include <hip/hip_bf16.h>

// Problem dims (fixed)
#define NROWS 8192   // N == M == 8192
#define DIM   512    // IN_FEATS == OUT_FEATS == 512

typedef short v8s __attribute__((ext_vector_type(8)));
typedef float v4f __attribute__((ext_vector_type(4)));

#define ASM_VMCNT(n) asm volatile("s_waitcnt vmcnt(" #n ")" ::: "memory")
#define ASM_LGKM0    asm volatile("s_waitcnt lgkmcnt(0)" ::: "memory")
#define ASM_FENCE    asm volatile("" ::: "memory")
#define BAR          __builtin_amdgcn_s_barrier()

__device__ __forceinline__ short f2bf(float f) {
    union { float f; unsigned u; } v; v.f = f;
    unsigned r = (v.u + 0x7fffu + ((v.u >> 16) & 1u)) >> 16;
    return (short)r;
}

__device__ __forceinline__ void stage16(const void* g, void* l) {
    typedef __attribute__((address_space(1))) const unsigned GA;
    typedef __attribute__((address_space(3))) unsigned LA;
    __builtin_amdgcn_global_load_lds((GA*)(const unsigned*)g, (LA*)(unsigned*)l, 16, 0, 0);
}

// ---------------------------------------------------------------------------
// Cast f32 [R][C] -> bf16 transposed [C][R]
// ---------------------------------------------------------------------------
__global__ __launch_bounds__(256) void transpose_cast_kernel(
        const float* __restrict__ in, short* __restrict__ out, int R, int C) {
    __shared__ float t[32][33];
    const int lx = threadIdx.x & 31;
    const int ly = threadIdx.x >> 5;
    const int r0 = blockIdx.x * 32;
    const int c0 = blockIdx.y * 32;
#pragma unroll
    for (int p = 0; p < 4; ++p)
        t[ly + 8 * p][lx] = in[(size_t)(r0 + ly + 8 * p) * C + c0 + lx];
    __syncthreads();
#pragma unroll
    for (int p = 0; p < 4; ++p)
        out[(size_t)(c0 + ly + 8 * p) * R + r0 + lx] = f2bf(t[lx][ly + 8 * p]);
}

// ---------------------------------------------------------------------------
// H = cast_bf16(F) @ W ; z selects (feat_p -> Hp) or (feat_s -> Hs)
// ---------------------------------------------------------------------------
__global__ __launch_bounds__(256) void gemm1_kernel(
        const float* __restrict__ Fp, const float* __restrict__ Fs,
        const short* __restrict__ WT,
        short* __restrict__ Hp, short* __restrict__ Hs) {
    const float* F = blockIdx.z ? Fs : Fp;
    short* H = blockIdx.z ? Hs : Hp;
    const int lane = threadIdx.x & 63;
    const int wid  = threadIdx.x >> 6;
    const int lr = lane & 15, lg = lane >> 4;
    const int r0 = blockIdx.x * 64 + wid * 16;
    const int c0 = blockIdx.y * 64;

    v4f acc[4] = {};
#pragma unroll
    for (int kc = 0; kc < 16; ++kc) {
        const int k = kc * 32 + lg * 8;
        const float* ap = F + (size_t)(r0 + lr) * DIM + k;
        float4 f0 = *(const float4*)ap;
        float4 f1 = *(const float4*)(ap + 4);
        v8s a;
        a[0] = f2bf(f0.x); a[1] = f2bf(f0.y); a[2] = f2bf(f0.z); a[3] = f2bf(f0.w);
        a[4] = f2bf(f1.x); a[5] = f2bf(f1.y); a[6] = f2bf(f1.z); a[7] = f2bf(f1.w);
#pragma unroll
        for (int ct = 0; ct < 4; ++ct) {
            v8s b = *(const v8s*)(WT + (size_t)(c0 + ct * 16 + lr) * DIM + k);
            acc[ct] = __builtin_amdgcn_mfma_f32_16x16x32_bf16(a, b, acc[ct], 0, 0, 0);
        }
    }
#pragma unroll
    for (int ct = 0; ct < 4; ++ct)
#pragma unroll
        for (int i = 0; i < 4; ++i)
            H[(size_t)(r0 + lg * 4 + i) * DIM + c0 + ct * 16 + lr] = f2bf(acc[ct][i]);
}

// ---------------------------------------------------------------------------
// Fused kernel, 1-barrier-per-jt pipeline, A-register-blocked phase A.
//   gfx950 accum_offset split: AGPR side holds accC (64) + afrag1 (64, pinned
//   via inline-asm "+a"); arch side holds afrag0 (64) + bF (32) + temps.
//   MFMA src operands are AV-class on gfx950, so AGPR-resident afrag1 feeds
//   v_mfma directly. This sidesteps the 128-arch-VGPR cap that spilled R4/R6.
// body(t): BAR; issue bF(t-1); issue stage(t+1);
//          phaseA(t) [1 LDS read -> 2 MFMA]; vmcnt(8) -> phaseB(t-1)
//          [stage in flight]; relu->Sb[t&1]; lgkm0; vmcnt(0).
// ---------------------------------------------------------------------------
#define JSPLIT 2
#define JT_PER_BLOCK (NROWS / 64 / JSPLIT)   // 64 j-tiles of 64

__device__ __forceinline__ void stage_full(const char* __restrict__ HsB,
        char* ringW, int j0, int tid) {
#pragma unroll
    for (int s = 0; s < 8; ++s) {
        const int L = s * 8192 + tid * 16;              // linear LDS byte offset
        const int row = L >> 10;                        // 1024 B per j-row
        const int c = (L & 1023) ^ ((row & 7) << 4);    // inverse swizzle (involution)
        stage16(HsB + ((size_t)(j0 + row) << 10) + c, ringW + L);
    }
}

__device__ __forceinline__ void phase_b(const short (*SbR)[72], const v8s* bF,
        v4f (&accC)[16], int lr, int lg) {
    __builtin_amdgcn_s_setprio(1);
#pragma unroll
    for (int kc2 = 0; kc2 < 2; ++kc2)
#pragma unroll
        for (int mt = 0; mt < 4; ++mt) {
            v8s aS = *(const v8s*)&SbR[mt * 16 + lr][kc2 * 32 + lg * 8];
#pragma unroll
            for (int ct = 0; ct < 4; ++ct)
                accC[mt * 4 + ct] = __builtin_amdgcn_mfma_f32_16x16x32_bf16(
                    aS, bF[ct * 2 + kc2], accC[mt * 4 + ct], 0, 0, 0);
        }
    __builtin_amdgcn_s_setprio(0);
}

__global__ __launch_bounds__(512, 2) void fused_kernel(
        const short* __restrict__ Hp, const short* __restrict__ Hs,
        const short* __restrict__ FsT, float* __restrict__ Cacc,
        float* __restrict__ ssq) {
    __shared__ __align__(16) short HsL[2][64][512];   // 2 x 64KB ring
    __shared__ __align__(16) short Sb[2][64][72];     // 2 x 9KB S-tile

    const int tid  = threadIdx.x;
    const int lane = tid & 63;
    const int wid  = tid >> 6;
    const int lr = lane & 15, lg = lane >> 4;
    const int ws = wid >> 2;       // m-halfstrip (0..1), 32 rows via 2 afrags
    const int jq = wid & 3;        // j-quarter (0..3), 16 cols

    // XCD-aware swizzle: 256 blocks, 8 XCDs -> contiguous chunks of 32
    const int nwg = gridDim.x * gridDim.y;
    const int bid = blockIdx.x + gridDim.x * blockIdx.y;
    const int cpx = nwg >> 3;
    const int swz = (bid & 7) * cpx + (bid >> 3);
    const int bx = swz % gridDim.x;
    const int by = swz / gridDim.x;

    const int m0  = bx * 64;
    const int jt0 = by * JT_PER_BLOCK;

    // A-fragments: 32 Hp rows (ws-halfstrip) x full K=512.
    // afrag0 stays in arch VGPRs (64); afrag1 is pinned to AGPRs (64).
    v8s afrag0[16], afrag1[16];
#pragma unroll
    for (int kk = 0; kk < 16; ++kk)
        afrag0[kk] = *(const v8s*)(Hp +
            (size_t)(m0 + ws * 32 + lr) * DIM + kk * 32 + lg * 8);
#pragma unroll
    for (int kk = 0; kk < 16; ++kk) {
        afrag1[kk] = *(const v8s*)(Hp +
            (size_t)(m0 + ws * 32 + 16 + lr) * DIM + kk * 32 + lg * 8);
        asm volatile("" : "+a"(afrag1[kk]));   // pin to AGPR side of the split
    }

    v4f accC[16] = {};
    float ssq_l = 0.f;

    stage_full((const char*)Hs, (char*)&HsL[0][0][0], jt0 * 64, tid);
    ASM_VMCNT(0);   // afrag + jt0 staging drained

    const int xo = (lr & 7) << 4;

    for (int t = 0; t < JT_PER_BLOCK; ++t) {
        const int jcur  = (jt0 + t) * 64;
        const int jnext = (t + 1 < JT_PER_BLOCK) ? jcur + 64 : jt0 * 64;
        const char* ringR = (const char*)&HsL[t & 1][0][0];
        char*       ringW = (char*)&HsL[(t + 1) & 1][0][0];

        BAR;   // ring[t&1] staged by all; Sb[(t-1)&1] published; prior readers done
        ASM_FENCE;

        // issue bF(t-1): consumed by phase B after phase A (latency hidden)
        v8s bF[8];
        if (t > 0) {
            const int jprev = jcur - 64;
#pragma unroll
            for (int ct = 0; ct < 4; ++ct)
#pragma unroll
                for (int kc2 = 0; kc2 < 2; ++kc2)
                    bF[ct * 2 + kc2] = *(const v8s*)(FsT +
                        (size_t)(wid * 64 + ct * 16 + lr) * NROWS + jprev + kc2 * 32 + lg * 8);
        }
        ASM_FENCE;   // pin vmem order: bF (oldest) then stage DMAs
        stage_full((const char*)Hs, ringW, jnext, tid);

        // ---- phase A(t): S[ws*32..+32][jq*16..+16] over K=512
        //      1 LDS read feeds 2 MFMAs (A-register blocking)
        v4f s0 = {}, s1 = {};
        {
            const char* rp = ringR + (size_t)(jq * 16 + lr) * 1024;
            __builtin_amdgcn_s_setprio(1);
#pragma unroll
            for (int kk = 0; kk < 16; ++kk) {
                v8s hb = *(const v8s*)(rp + ((kk * 64 + lg * 16) ^ xo));
                s0 = __builtin_amdgcn_mfma_f32_16x16x32_bf16(afrag0[kk], hb, s0, 0, 0, 0);
                s1 = __builtin_amdgcn_mfma_f32_16x16x32_bf16(afrag1[kk], hb, s1, 0, 0, 0);
            }
            __builtin_amdgcn_s_setprio(0);
        }

        // ---- phase B(t-1): bF ready by now; stage DMAs stay in flight
        if (t > 0) {
            ASM_VMCNT(8);
            phase_b(Sb[(t - 1) & 1], bF, accC, lr, lg);
        }

        // ---- relu + ssq + Sb[t&1] write
        short (*SbW)[72] = Sb[t & 1];
#pragma unroll
        for (int i = 0; i < 4; ++i) {
            float v0 = fmaxf(s0[i], 0.f), v1 = fmaxf(s1[i], 0.f);
            ssq_l += v0 * v0 + v1 * v1;
            SbW[ws * 32 + lg * 4 + i][jq * 16 + lr]      = f2bf(v0);
            SbW[ws * 32 + 16 + lg * 4 + i][jq * 16 + lr] = f2bf(v1);
        }
        ASM_LGKM0;      // ring reads + Sb writes drained (publish at next BAR)
        ASM_VMCNT(0);   // own stage(t+1) DMAs landed
    }

    // ---- final phase B for t = JT_PER_BLOCK-1
    BAR;
    {
        const int jprev = (jt0 + JT_PER_BLOCK - 1) * 64;
        v8s bF[8];
#pragma unroll
        for (int ct = 0; ct < 4; ++ct)
#pragma unroll
            for (int kc2 = 0; kc2 < 2; ++kc2)
                bF[ct * 2 + kc2] = *(const v8s*)(FsT +
                    (size_t)(wid * 64 + ct * 16 + lr) * NROWS + jprev + kc2 * 32 + lg * 8);
        ASM_VMCNT(0);
        phase_b(Sb[(JT_PER_BLOCK - 1) & 1], bF, accC, lr, lg);
    }

    // ---- epilogue
    float w = ssq_l;
#pragma unroll
    for (int off = 32; off; off >>= 1) w += __shfl_down(w, off);
    if (lane == 0) atomicAdd(ssq, w);

#pragma unroll
    for (int mt = 0; mt < 4; ++mt)
#pragma unroll
        for (int ct = 0; ct < 4; ++ct)
#pragma unroll
            for (int i = 0; i < 4; ++i)
                atomicAdd(&Cacc[(size_t)(m0 + mt * 16 + lg * 4 + i) * DIM +
                                wid * 64 + ct * 16 + lr],
                          accC[mt * 4 + ct][i]);
}

// ---------------------------------------------------------------------------
__global__ __launch_bounds__(256) void scale_kernel(float* __restrict__ C,
                                                    const float* __restrict__ ssq) {
    const float rs = 1.0f / sqrtf(*ssq);
    const size_t i = (size_t)blockIdx.x * blockDim.x + threadIdx.x;
    float4* p = (float4*)C;
    float4 v = p[i];
    v.x *= rs; v.y *= rs; v.z *= rs; v.w *= rs;
    p[i] = v;
}

// ---------------------------------------------------------------------------
extern "C" void kernel_launch(void* const* d_in, const int* in_sizes, int n_in,
                              void* d_out, int out_size, void* d_ws, size_t ws_size,
                              hipStream_t stream) {
    const float* feat_p   = (const float*)d_in[0];
    const float* feat_s   = (const float*)d_in[1];
    const float* weight_a = (const float*)d_in[2];

    char* ws = (char*)d_ws;
    float* ssqp = (float*)ws;                                  // 4 B
    short* WT   = (short*)(ws + 512);                          // 512 KB
    short* Hp   = (short*)(ws + 512 + 524288);                 // 8 MB
    short* Hs   = (short*)(ws + 512 + 524288 + 8388608);       // 8 MB
    short* FsT  = (short*)(ws + 512 + 524288 + 16777216);      // 8 MB [DIM][NROWS]

    transpose_cast_kernel<<<dim3(DIM / 32, DIM / 32), 256, 0, stream>>>(weight_a, WT, DIM, DIM);
    transpose_cast_kernel<<<dim3(NROWS / 32, DIM / 32), 256, 0, stream>>>(feat_s, FsT, NROWS, DIM);

    gemm1_kernel<<<dim3(NROWS / 64, DIM / 64, 2), 256, 0, stream>>>(
        feat_p, feat_s, WT, Hp, Hs);

    hipMemsetAsync(d_out, 0, (size_t)out_size * sizeof(float), stream);
    hipMemsetAsync(ssqp, 0, sizeof(float), stream);

    fused_kernel<<<dim3(NROWS / 64, JSPLIT), 512, 0, stream>>>(Hp, Hs, FsT, (float*)d_out, ssqp);

    scale_kernel<<<(out_size / 4 + 255) / 256, 256, 0, stream>>>((float*)d_out, ssqp);
}

// Round 9
// 353.012 us; speedup vs baseline: 1.3598x; 1.3598x over previous
//
#include <hip/hip_runtime.h>
#include <hip/hip_bf16.h>

// Problem dims (fixed)
#define NROWS 8192   // N == M == 8192
#define DIM   512    // IN_FEATS == OUT_FEATS == 512

typedef short v8s __attribute__((ext_vector_type(8)));
typedef float v4f __attribute__((ext_vector_type(4)));

#define ASM_VMCNT(n) asm volatile("s_waitcnt vmcnt(" #n ")" ::: "memory")
#define ASM_LGKM0    asm volatile("s_waitcnt lgkmcnt(0)" ::: "memory")
#define ASM_FENCE    asm volatile("" ::: "memory")
#define BAR          __builtin_amdgcn_s_barrier()

__device__ __forceinline__ short f2bf(float f) {
    union { float f; unsigned u; } v; v.f = f;
    unsigned r = (v.u + 0x7fffu + ((v.u >> 16) & 1u)) >> 16;
    return (short)r;
}

__device__ __forceinline__ void stage16(const void* g, void* l) {
    typedef __attribute__((address_space(1))) const unsigned GA;
    typedef __attribute__((address_space(3))) unsigned LA;
    __builtin_amdgcn_global_load_lds((GA*)(const unsigned*)g, (LA*)(unsigned*)l, 16, 0, 0);
}

// ---------------------------------------------------------------------------
// Cast f32 [R][C] -> bf16 transposed [C][R]
// ---------------------------------------------------------------------------
__global__ __launch_bounds__(256) void transpose_cast_kernel(
        const float* __restrict__ in, short* __restrict__ out, int R, int C) {
    __shared__ float t[32][33];
    const int lx = threadIdx.x & 31;
    const int ly = threadIdx.x >> 5;
    const int r0 = blockIdx.x * 32;
    const int c0 = blockIdx.y * 32;
#pragma unroll
    for (int p = 0; p < 4; ++p)
        t[ly + 8 * p][lx] = in[(size_t)(r0 + ly + 8 * p) * C + c0 + lx];
    __syncthreads();
#pragma unroll
    for (int p = 0; p < 4; ++p)
        out[(size_t)(c0 + ly + 8 * p) * R + r0 + lx] = f2bf(t[lx][ly + 8 * p]);
}

// ---------------------------------------------------------------------------
// H = cast_bf16(F) @ W ; z selects (feat_p -> Hp) or (feat_s -> Hs)
// v2: 512-thr blocks, 128 m-rows x 256 n-cols per block (grid 64 x 2 x 2).
// F (f32) is read ONCE per n-half (2x total vs 8x in v1); afrag per wave is
// built once (64 VGPR); inner loop = ct-pairs (2 indep MFMA chains).
// ---------------------------------------------------------------------------
__global__ __launch_bounds__(512) void gemm1_kernel(
        const float* __restrict__ Fp, const float* __restrict__ Fs,
        const short* __restrict__ WT,
        short* __restrict__ Hp, short* __restrict__ Hs) {
    const float* F = blockIdx.z ? Fs : Fp;
    short* H = blockIdx.z ? Hs : Hp;
    const int lane = threadIdx.x & 63;
    const int wid  = threadIdx.x >> 6;          // 0..7
    const int lr = lane & 15, lg = lane >> 4;
    const int r0 = blockIdx.x * 128 + wid * 16; // gridDim.x = 64
    const int c0 = blockIdx.y * 256;            // gridDim.y = 2

    // A-fragments: 16 rows x K=512, f32 -> bf16 once (64 VGPR)
    v8s a[16];
#pragma unroll
    for (int kk = 0; kk < 16; ++kk) {
        const float* ap = F + (size_t)(r0 + lr) * DIM + kk * 32 + lg * 8;
        float4 f0 = *(const float4*)ap;
        float4 f1 = *(const float4*)(ap + 4);
        v8s t;
        t[0] = f2bf(f0.x); t[1] = f2bf(f0.y); t[2] = f2bf(f0.z); t[3] = f2bf(f0.w);
        t[4] = f2bf(f1.x); t[5] = f2bf(f1.y); t[6] = f2bf(f1.z); t[7] = f2bf(f1.w);
        a[kk] = t;
    }

    for (int ctp = 0; ctp < 8; ++ctp) {
        const int cb = c0 + ctp * 32;
        v4f acc0 = {}, acc1 = {};
#pragma unroll
        for (int kk = 0; kk < 16; ++kk) {
            v8s b0 = *(const v8s*)(WT + (size_t)(cb + lr) * DIM + kk * 32 + lg * 8);
            v8s b1 = *(const v8s*)(WT + (size_t)(cb + 16 + lr) * DIM + kk * 32 + lg * 8);
            acc0 = __builtin_amdgcn_mfma_f32_16x16x32_bf16(a[kk], b0, acc0, 0, 0, 0);
            acc1 = __builtin_amdgcn_mfma_f32_16x16x32_bf16(a[kk], b1, acc1, 0, 0, 0);
        }
#pragma unroll
        for (int i = 0; i < 4; ++i) {
            H[(size_t)(r0 + lg * 4 + i) * DIM + cb + lr]      = f2bf(acc0[i]);
            H[(size_t)(r0 + lg * 4 + i) * DIM + cb + 16 + lr] = f2bf(acc1[i]);
        }
    }
}

// ---------------------------------------------------------------------------
// Fused kernel (R5 structure + bF cross-body prefetch + relu-before-phaseB):
//   ring[2] = two full 64x512 Hs jt-tiles (128 KB, XOR-swizzled storage)
//   Sb[2]   = double-buffered bf16 S-tile
// body(t): BAR; issue stage(t+1); phaseA(t); relu->Sb[t&1];
//          vmcnt(8) [drains bF(t-1), stage stays]; phaseB(t-1); lgkm0;
//          issue bF(t) [rides across BAR]; vmcnt(8) [drains stage, keeps bF].
// Phase A wave = (strip=wid>>1: 16 m-rows, half=wid&1: 32 j-cols), afrag[16].
// Phase B wave owns 64 C-cols.
// ---------------------------------------------------------------------------
#define JSPLIT 2
#define JT_PER_BLOCK (NROWS / 64 / JSPLIT)   // 64 j-tiles of 64

__device__ __forceinline__ void stage_full(const char* __restrict__ HsB,
        char* ringW, int j0, int tid) {
#pragma unroll
    for (int s = 0; s < 8; ++s) {
        const int L = s * 8192 + tid * 16;              // linear LDS byte offset
        const int row = L >> 10;                        // 1024 B per j-row
        const int c = (L & 1023) ^ ((row & 7) << 4);    // inverse swizzle (involution)
        stage16(HsB + ((size_t)(j0 + row) << 10) + c, ringW + L);
    }
}

__device__ __forceinline__ void phase_b(const short (*SbR)[72], const v8s* bF,
        v4f (&accC)[16], int lr, int lg) {
    __builtin_amdgcn_s_setprio(1);
#pragma unroll
    for (int kc2 = 0; kc2 < 2; ++kc2)
#pragma unroll
        for (int mt = 0; mt < 4; ++mt) {
            v8s aS = *(const v8s*)&SbR[mt * 16 + lr][kc2 * 32 + lg * 8];
#pragma unroll
            for (int ct = 0; ct < 4; ++ct)
                accC[mt * 4 + ct] = __builtin_amdgcn_mfma_f32_16x16x32_bf16(
                    aS, bF[ct * 2 + kc2], accC[mt * 4 + ct], 0, 0, 0);
        }
    __builtin_amdgcn_s_setprio(0);
}

__global__ __launch_bounds__(512, 2) void fused_kernel(
        const short* __restrict__ Hp, const short* __restrict__ Hs,
        const short* __restrict__ FsT, float* __restrict__ Cacc,
        float* __restrict__ ssq) {
    __shared__ __align__(16) short HsL[2][64][512];   // 2 x 64KB ring
    __shared__ __align__(16) short Sb[2][64][72];     // 2 x 9KB S-tile

    const int tid  = threadIdx.x;
    const int lane = tid & 63;
    const int wid  = tid >> 6;
    const int lr = lane & 15, lg = lane >> 4;
    const int strip = wid >> 1;    // m-strip (0..3), 16 rows
    const int half  = wid & 1;     // j-half (0..1), 32 cols

    // XCD-aware swizzle: 256 blocks, 8 XCDs -> contiguous chunks of 32
    const int nwg = gridDim.x * gridDim.y;
    const int bid = blockIdx.x + gridDim.x * blockIdx.y;
    const int cpx = nwg >> 3;
    const int swz = (bid & 7) * cpx + (bid >> 3);
    const int bx = swz % gridDim.x;
    const int by = swz / gridDim.x;

    const int m0  = bx * 64;
    const int jt0 = by * JT_PER_BLOCK;

    // A-fragments: 16 Hp rows (strip) x full K=512 -> 64 VGPR
    v8s afrag[16];
#pragma unroll
    for (int kk = 0; kk < 16; ++kk)
        afrag[kk] = *(const v8s*)(Hp +
            (size_t)(m0 + strip * 16 + lr) * DIM + kk * 32 + lg * 8);

    v4f accC[16] = {};
    v8s bF[8];
    float ssq_l = 0.f;

    stage_full((const char*)Hs, (char*)&HsL[0][0][0], jt0 * 64, tid);
    ASM_VMCNT(0);   // afrag + jt0 staging drained

    const int xo = (lr & 7) << 4;

    for (int t = 0; t < JT_PER_BLOCK; ++t) {
        const int jcur  = (jt0 + t) * 64;
        const int jnext = (t + 1 < JT_PER_BLOCK) ? jcur + 64 : jt0 * 64;
        const char* ringR = (const char*)&HsL[t & 1][0][0];
        char*       ringW = (char*)&HsL[(t + 1) & 1][0][0];

        BAR;   // ring[t&1] staged by all; Sb[(t-1)&1] published; prior readers done
        ASM_FENCE;

        // issue staging for next jt (stays in flight through this body)
        stage_full((const char*)Hs, ringW, jnext, tid);

        // ---- phase A(t): S[strip*16..+16][half*32..+32] over K=512
        v4f s0 = {}, s1 = {};
        {
            const char* rp0 = ringR + (size_t)(half * 32 + lr) * 1024;
            const char* rp1 = rp0 + 16 * 1024;
            __builtin_amdgcn_s_setprio(1);
#pragma unroll
            for (int kk = 0; kk < 16; ++kk) {
                const int off = (kk * 64 + lg * 16) ^ xo;
                v8s hb0 = *(const v8s*)(rp0 + off);
                v8s hb1 = *(const v8s*)(rp1 + off);
                s0 = __builtin_amdgcn_mfma_f32_16x16x32_bf16(afrag[kk], hb0, s0, 0, 0, 0);
                s1 = __builtin_amdgcn_mfma_f32_16x16x32_bf16(afrag[kk], hb1, s1, 0, 0, 0);
            }
            __builtin_amdgcn_s_setprio(0);
        }

        // ---- relu + ssq + Sb[t&1] write
        short (*SbW)[72] = Sb[t & 1];
#pragma unroll
        for (int i = 0; i < 4; ++i) {
            float v0 = fmaxf(s0[i], 0.f), v1 = fmaxf(s1[i], 0.f);
            ssq_l += v0 * v0 + v1 * v1;
            const int r = strip * 16 + lg * 4 + i;
            SbW[r][(half * 2 + 0) * 16 + lr] = f2bf(v0);
            SbW[r][(half * 2 + 1) * 16 + lr] = f2bf(v1);
        }

        // ---- phase B(t-1): bF(t-1) issued last body, fully landed by now
        if (t > 0) {
            ASM_VMCNT(8);   // drains bF(t-1) (oldest 8); stage(t+1) stays
            phase_b(Sb[(t - 1) & 1], bF, accC, lr, lg);
        }
        ASM_LGKM0;          // ring reads + Sb writes drained (publish at next BAR)

        // ---- issue bF(t) for next body's phase B (rides across the barrier)
        ASM_FENCE;
#pragma unroll
        for (int ct = 0; ct < 4; ++ct)
#pragma unroll
            for (int kc2 = 0; kc2 < 2; ++kc2)
                bF[ct * 2 + kc2] = *(const v8s*)(FsT +
                    (size_t)(wid * 64 + ct * 16 + lr) * NROWS + jcur + kc2 * 32 + lg * 8);
        ASM_VMCNT(8);       // drains stage(t+1) (older); bF(t) stays in flight
    }

    // ---- final phase B for t = JT_PER_BLOCK-1 (bF already in flight)
    BAR;
    ASM_VMCNT(0);
    phase_b(Sb[(JT_PER_BLOCK - 1) & 1], bF, accC, lr, lg);

    // ---- epilogue
    float w = ssq_l;
#pragma unroll
    for (int off = 32; off; off >>= 1) w += __shfl_down(w, off);
    if (lane == 0) atomicAdd(ssq, w);

#pragma unroll
    for (int mt = 0; mt < 4; ++mt)
#pragma unroll
        for (int ct = 0; ct < 4; ++ct)
#pragma unroll
            for (int i = 0; i < 4; ++i)
                atomicAdd(&Cacc[(size_t)(m0 + mt * 16 + lg * 4 + i) * DIM +
                                wid * 64 + ct * 16 + lr],
                          accC[mt * 4 + ct][i]);
}

// ---------------------------------------------------------------------------
__global__ __launch_bounds__(256) void scale_kernel(float* __restrict__ C,
                                                    const float* __restrict__ ssq) {
    const float rs = 1.0f / sqrtf(*ssq);
    const size_t i = (size_t)blockIdx.x * blockDim.x + threadIdx.x;
    float4* p = (float4*)C;
    float4 v = p[i];
    v.x *= rs; v.y *= rs; v.z *= rs; v.w *= rs;
    p[i] = v;
}

// ---------------------------------------------------------------------------
extern "C" void kernel_launch(void* const* d_in, const int* in_sizes, int n_in,
                              void* d_out, int out_size, void* d_ws, size_t ws_size,
                              hipStream_t stream) {
    const float* feat_p   = (const float*)d_in[0];
    const float* feat_s   = (const float*)d_in[1];
    const float* weight_a = (const float*)d_in[2];

    char* ws = (char*)d_ws;
    float* ssqp = (float*)ws;                                  // 4 B
    short* WT   = (short*)(ws + 512);                          // 512 KB
    short* Hp   = (short*)(ws + 512 + 524288);                 // 8 MB
    short* Hs   = (short*)(ws + 512 + 524288 + 8388608);       // 8 MB
    short* FsT  = (short*)(ws + 512 + 524288 + 16777216);      // 8 MB [DIM][NROWS]

    transpose_cast_kernel<<<dim3(DIM / 32, DIM / 32), 256, 0, stream>>>(weight_a, WT, DIM, DIM);
    transpose_cast_kernel<<<dim3(NROWS / 32, DIM / 32), 256, 0, stream>>>(feat_s, FsT, NROWS, DIM);

    gemm1_kernel<<<dim3(NROWS / 128, 2, 2), 512, 0, stream>>>(
        feat_p, feat_s, WT, Hp, Hs);

    hipMemsetAsync(d_out, 0, (size_t)out_size * sizeof(float), stream);
    hipMemsetAsync(ssqp, 0, sizeof(float), stream);

    fused_kernel<<<dim3(NROWS / 64, JSPLIT), 512, 0, stream>>>(Hp, Hs, FsT, (float*)d_out, ssqp);

    scale_kernel<<<(out_size / 4 + 255) / 256, 256, 0, stream>>>((float*)d_out, ssqp);
}

// Round 10
// 351.173 us; speedup vs baseline: 1.3669x; 1.0052x over previous
//
#include <hip/hip_runtime.h>
#include <hip/hip_bf16.h>

// Problem dims (fixed)
#define NROWS 8192   // N == M == 8192
#define DIM   512    // IN_FEATS == OUT_FEATS == 512

typedef short v8s __attribute__((ext_vector_type(8)));
typedef float v4f __attribute__((ext_vector_type(4)));

#define ASM_VMCNT(n) asm volatile("s_waitcnt vmcnt(" #n ")" ::: "memory")
#define ASM_LGKM0    asm volatile("s_waitcnt lgkmcnt(0)" ::: "memory")
#define ASM_FENCE    asm volatile("" ::: "memory")
#define BAR          __builtin_amdgcn_s_barrier()

__device__ __forceinline__ short f2bf(float f) {
    union { float f; unsigned u; } v; v.f = f;
    unsigned r = (v.u + 0x7fffu + ((v.u >> 16) & 1u)) >> 16;
    return (short)r;
}

__device__ __forceinline__ void stage16(const void* g, void* l) {
    typedef __attribute__((address_space(1))) const unsigned GA;
    typedef __attribute__((address_space(3))) unsigned LA;
    __builtin_amdgcn_global_load_lds((GA*)(const unsigned*)g, (LA*)(unsigned*)l, 16, 0, 0);
}

// ---------------------------------------------------------------------------
// Cast f32 [R][C] -> bf16 transposed [C][R]
// ---------------------------------------------------------------------------
__global__ __launch_bounds__(256) void transpose_cast_kernel(
        const float* __restrict__ in, short* __restrict__ out, int R, int C) {
    __shared__ float t[32][33];
    const int lx = threadIdx.x & 31;
    const int ly = threadIdx.x >> 5;
    const int r0 = blockIdx.x * 32;
    const int c0 = blockIdx.y * 32;
#pragma unroll
    for (int p = 0; p < 4; ++p)
        t[ly + 8 * p][lx] = in[(size_t)(r0 + ly + 8 * p) * C + c0 + lx];
    __syncthreads();
#pragma unroll
    for (int p = 0; p < 4; ++p)
        out[(size_t)(c0 + ly + 8 * p) * R + r0 + lx] = f2bf(t[lx][ly + 8 * p]);
}

// ---------------------------------------------------------------------------
// H = cast_bf16(F) @ W ; z selects (feat_p -> Hp) or (feat_s -> Hs)
// v2: 512-thr blocks, 128 m-rows x 256 n-cols per block (grid 64 x 2 x 2).
// ---------------------------------------------------------------------------
__global__ __launch_bounds__(512) void gemm1_kernel(
        const float* __restrict__ Fp, const float* __restrict__ Fs,
        const short* __restrict__ WT,
        short* __restrict__ Hp, short* __restrict__ Hs) {
    const float* F = blockIdx.z ? Fs : Fp;
    short* H = blockIdx.z ? Hs : Hp;
    const int lane = threadIdx.x & 63;
    const int wid  = threadIdx.x >> 6;          // 0..7
    const int lr = lane & 15, lg = lane >> 4;
    const int r0 = blockIdx.x * 128 + wid * 16; // gridDim.x = 64
    const int c0 = blockIdx.y * 256;            // gridDim.y = 2

    v8s a[16];
#pragma unroll
    for (int kk = 0; kk < 16; ++kk) {
        const float* ap = F + (size_t)(r0 + lr) * DIM + kk * 32 + lg * 8;
        float4 f0 = *(const float4*)ap;
        float4 f1 = *(const float4*)(ap + 4);
        v8s t;
        t[0] = f2bf(f0.x); t[1] = f2bf(f0.y); t[2] = f2bf(f0.z); t[3] = f2bf(f0.w);
        t[4] = f2bf(f1.x); t[5] = f2bf(f1.y); t[6] = f2bf(f1.z); t[7] = f2bf(f1.w);
        a[kk] = t;
    }

    for (int ctp = 0; ctp < 8; ++ctp) {
        const int cb = c0 + ctp * 32;
        v4f acc0 = {}, acc1 = {};
#pragma unroll
        for (int kk = 0; kk < 16; ++kk) {
            v8s b0 = *(const v8s*)(WT + (size_t)(cb + lr) * DIM + kk * 32 + lg * 8);
            v8s b1 = *(const v8s*)(WT + (size_t)(cb + 16 + lr) * DIM + kk * 32 + lg * 8);
            acc0 = __builtin_amdgcn_mfma_f32_16x16x32_bf16(a[kk], b0, acc0, 0, 0, 0);
            acc1 = __builtin_amdgcn_mfma_f32_16x16x32_bf16(a[kk], b1, acc1, 0, 0, 0);
        }
#pragma unroll
        for (int i = 0; i < 4; ++i) {
            H[(size_t)(r0 + lg * 4 + i) * DIM + cb + lr]      = f2bf(acc0[i]);
            H[(size_t)(r0 + lg * 4 + i) * DIM + cb + 16 + lr] = f2bf(acc1[i]);
        }
    }
}

// ---------------------------------------------------------------------------
// Fused kernel (R9 + phase-A/phase-B interleave):
//   ring[2] = two full 64x512 Hs jt-tiles (128 KB, XOR-swizzled storage)
//   Sb[2]   = double-buffered bf16 S-tile
// body(t): BAR; issue stage(t+1); A-prefix kk0..7; vmcnt(8) [drains bF(t-1),
//          in-order, keeps stage]; 8 groups { A-kk(8+g) || aS read + 4 B-MFMA
//          of phaseB(t-1) }; relu->Sb[t&1]; lgkm0; issue bF(t); vmcnt(8)
//          [drains stage(t+1), keeps bF(t) in flight across the BAR].
// ---------------------------------------------------------------------------
#define JSPLIT 2
#define JT_PER_BLOCK (NROWS / 64 / JSPLIT)   // 64 j-tiles of 64

__device__ __forceinline__ void stage_full(const char* __restrict__ HsB,
        char* ringW, int j0, int tid) {
#pragma unroll
    for (int s = 0; s < 8; ++s) {
        const int L = s * 8192 + tid * 16;              // linear LDS byte offset
        const int row = L >> 10;                        // 1024 B per j-row
        const int c = (L & 1023) ^ ((row & 7) << 4);    // inverse swizzle (involution)
        stage16(HsB + ((size_t)(j0 + row) << 10) + c, ringW + L);
    }
}

__device__ __forceinline__ void load_bF(v8s (&bF)[8], const short* __restrict__ FsT,
        int j, int wid, int lr, int lg) {
#pragma unroll
    for (int ct = 0; ct < 4; ++ct)
#pragma unroll
        for (int kc2 = 0; kc2 < 2; ++kc2)
            bF[ct * 2 + kc2] = *(const v8s*)(FsT +
                (size_t)(wid * 64 + ct * 16 + lr) * NROWS + j + kc2 * 32 + lg * 8);
}

__device__ __forceinline__ void phase_b(const short (*SbR)[72], const v8s* bF,
        v4f (&accC)[16], int lr, int lg) {
    __builtin_amdgcn_s_setprio(1);
#pragma unroll
    for (int kc2 = 0; kc2 < 2; ++kc2)
#pragma unroll
        for (int mt = 0; mt < 4; ++mt) {
            v8s aS = *(const v8s*)&SbR[mt * 16 + lr][kc2 * 32 + lg * 8];
#pragma unroll
            for (int ct = 0; ct < 4; ++ct)
                accC[mt * 4 + ct] = __builtin_amdgcn_mfma_f32_16x16x32_bf16(
                    aS, bF[ct * 2 + kc2], accC[mt * 4 + ct], 0, 0, 0);
        }
    __builtin_amdgcn_s_setprio(0);
}

__global__ __launch_bounds__(512, 2) void fused_kernel(
        const short* __restrict__ Hp, const short* __restrict__ Hs,
        const short* __restrict__ FsT, float* __restrict__ Cacc,
        float* __restrict__ ssq) {
    __shared__ __align__(16) short HsL[2][64][512];   // 2 x 64KB ring
    __shared__ __align__(16) short Sb[2][64][72];     // 2 x 9KB S-tile

    const int tid  = threadIdx.x;
    const int lane = tid & 63;
    const int wid  = tid >> 6;
    const int lr = lane & 15, lg = lane >> 4;
    const int strip = wid >> 1;    // m-strip (0..3), 16 rows
    const int half  = wid & 1;     // j-half (0..1), 32 cols

    // XCD-aware swizzle: 256 blocks, 8 XCDs -> contiguous chunks of 32
    const int nwg = gridDim.x * gridDim.y;
    const int bid = blockIdx.x + gridDim.x * blockIdx.y;
    const int cpx = nwg >> 3;
    const int swz = (bid & 7) * cpx + (bid >> 3);
    const int bx = swz % gridDim.x;
    const int by = swz / gridDim.x;

    const int m0  = bx * 64;
    const int jt0 = by * JT_PER_BLOCK;

    // A-fragments: 16 Hp rows (strip) x full K=512 -> 64 VGPR
    v8s afrag[16];
#pragma unroll
    for (int kk = 0; kk < 16; ++kk)
        afrag[kk] = *(const v8s*)(Hp +
            (size_t)(m0 + strip * 16 + lr) * DIM + kk * 32 + lg * 8);

    v4f accC[16] = {};
    v8s bF[8];
    float ssq_l = 0.f;

    stage_full((const char*)Hs, (char*)&HsL[0][0][0], jt0 * 64, tid);
    ASM_VMCNT(0);   // afrag + jt0 staging drained

    const int xo = (lr & 7) << 4;
    const char* rbase0;
    {
        // per-wave phase-A read bases (row within ring tile)
        // rp0 = ring + (half*32+lr)*1024 ; rp1 = rp0 + 16KB
    }

    // ---- peeled body t = 0 (no phase B)
    {
        const char* ringR = (const char*)&HsL[0][0][0];
        char*       ringW = (char*)&HsL[1][0][0];
        BAR; ASM_FENCE;
        stage_full((const char*)Hs, ringW, (jt0 + 1) * 64, tid);

        v4f s0 = {}, s1 = {};
        const char* rp0 = ringR + (size_t)(half * 32 + lr) * 1024;
        const char* rp1 = rp0 + 16 * 1024;
        __builtin_amdgcn_s_setprio(1);
#pragma unroll
        for (int kk = 0; kk < 16; ++kk) {
            const int off = (kk * 64 + lg * 16) ^ xo;
            v8s hb0 = *(const v8s*)(rp0 + off);
            v8s hb1 = *(const v8s*)(rp1 + off);
            s0 = __builtin_amdgcn_mfma_f32_16x16x32_bf16(afrag[kk], hb0, s0, 0, 0, 0);
            s1 = __builtin_amdgcn_mfma_f32_16x16x32_bf16(afrag[kk], hb1, s1, 0, 0, 0);
        }
        __builtin_amdgcn_s_setprio(0);

        short (*SbW)[72] = Sb[0];
#pragma unroll
        for (int i = 0; i < 4; ++i) {
            float v0 = fmaxf(s0[i], 0.f), v1 = fmaxf(s1[i], 0.f);
            ssq_l += v0 * v0 + v1 * v1;
            const int r = strip * 16 + lg * 4 + i;
            SbW[r][(half * 2 + 0) * 16 + lr] = f2bf(v0);
            SbW[r][(half * 2 + 1) * 16 + lr] = f2bf(v1);
        }
        ASM_LGKM0;
        ASM_FENCE;
        load_bF(bF, FsT, jt0 * 64, wid, lr, lg);
        ASM_VMCNT(8);   // stage(t=1) retired; bF in flight across the BAR
    }

    // ---- main loop t = 1 .. JT-1 : A(t) interleaved with B(t-1)
    for (int t = 1; t < JT_PER_BLOCK; ++t) {
        const int jcur  = (jt0 + t) * 64;
        const int jnext = (t + 1 < JT_PER_BLOCK) ? jcur + 64 : jt0 * 64;
        const char* ringR = (const char*)&HsL[t & 1][0][0];
        char*       ringW = (char*)&HsL[(t + 1) & 1][0][0];
        const short (*SbR)[72] = Sb[(t & 1) ^ 1];

        BAR; ASM_FENCE;   // ring[t&1] + Sb[(t-1)&1] published; prior readers done
        stage_full((const char*)Hs, ringW, jnext, tid);

        v4f s0 = {}, s1 = {};
        const char* rp0 = ringR + (size_t)(half * 32 + lr) * 1024;
        const char* rp1 = rp0 + 16 * 1024;
        __builtin_amdgcn_s_setprio(1);

        // A prefix: kk 0..7 (covers residual bF latency)
#pragma unroll
        for (int kk = 0; kk < 8; ++kk) {
            const int off = (kk * 64 + lg * 16) ^ xo;
            v8s hb0 = *(const v8s*)(rp0 + off);
            v8s hb1 = *(const v8s*)(rp1 + off);
            s0 = __builtin_amdgcn_mfma_f32_16x16x32_bf16(afrag[kk], hb0, s0, 0, 0, 0);
            s1 = __builtin_amdgcn_mfma_f32_16x16x32_bf16(afrag[kk], hb1, s1, 0, 0, 0);
        }

        ASM_VMCNT(8);   // in-order retire: bF(t-1) valid; stage(t+1) stays

        // 8 fused groups: A kk=8+g  ||  B group g (mt=g&3, kc2=g>>2)
#pragma unroll
        for (int g = 0; g < 8; ++g) {
            const int kk = 8 + g;
            const int off = (kk * 64 + lg * 16) ^ xo;
            v8s hb0 = *(const v8s*)(rp0 + off);
            v8s hb1 = *(const v8s*)(rp1 + off);
            s0 = __builtin_amdgcn_mfma_f32_16x16x32_bf16(afrag[kk], hb0, s0, 0, 0, 0);
            s1 = __builtin_amdgcn_mfma_f32_16x16x32_bf16(afrag[kk], hb1, s1, 0, 0, 0);

            const int mt = g & 3, kc2 = g >> 2;
            v8s aS = *(const v8s*)&SbR[mt * 16 + lr][kc2 * 32 + lg * 8];
#pragma unroll
            for (int ct = 0; ct < 4; ++ct)
                accC[mt * 4 + ct] = __builtin_amdgcn_mfma_f32_16x16x32_bf16(
                    aS, bF[ct * 2 + kc2], accC[mt * 4 + ct], 0, 0, 0);
        }
        __builtin_amdgcn_s_setprio(0);

        // relu + ssq + Sb[t&1] write
        short (*SbW)[72] = Sb[t & 1];
#pragma unroll
        for (int i = 0; i < 4; ++i) {
            float v0 = fmaxf(s0[i], 0.f), v1 = fmaxf(s1[i], 0.f);
            ssq_l += v0 * v0 + v1 * v1;
            const int r = strip * 16 + lg * 4 + i;
            SbW[r][(half * 2 + 0) * 16 + lr] = f2bf(v0);
            SbW[r][(half * 2 + 1) * 16 + lr] = f2bf(v1);
        }
        ASM_LGKM0;      // ring reads + Sb writes drained (publish at next BAR)

        // issue bF(t) for next body (rides across the barrier)
        ASM_FENCE;
        load_bF(bF, FsT, jcur, wid, lr, lg);
        ASM_VMCNT(8);   // stage(t+1) retired; bF(t) stays in flight
    }

    // ---- final phase B for t = JT-1 (bF already in flight)
    BAR;
    ASM_VMCNT(0);
    phase_b(Sb[(JT_PER_BLOCK - 1) & 1], bF, accC, lr, lg);

    // ---- epilogue
    float w = ssq_l;
#pragma unroll
    for (int off = 32; off; off >>= 1) w += __shfl_down(w, off);
    if (lane == 0) atomicAdd(ssq, w);

#pragma unroll
    for (int mt = 0; mt < 4; ++mt)
#pragma unroll
        for (int ct = 0; ct < 4; ++ct)
#pragma unroll
            for (int i = 0; i < 4; ++i)
                atomicAdd(&Cacc[(size_t)(m0 + mt * 16 + lg * 4 + i) * DIM +
                                wid * 64 + ct * 16 + lr],
                          accC[mt * 4 + ct][i]);
}

// ---------------------------------------------------------------------------
__global__ __launch_bounds__(256) void scale_kernel(float* __restrict__ C,
                                                    const float* __restrict__ ssq) {
    const float rs = 1.0f / sqrtf(*ssq);
    const size_t i = (size_t)blockIdx.x * blockDim.x + threadIdx.x;
    float4* p = (float4*)C;
    float4 v = p[i];
    v.x *= rs; v.y *= rs; v.z *= rs; v.w *= rs;
    p[i] = v;
}

// ---------------------------------------------------------------------------
extern "C" void kernel_launch(void* const* d_in, const int* in_sizes, int n_in,
                              void* d_out, int out_size, void* d_ws, size_t ws_size,
                              hipStream_t stream) {
    const float* feat_p   = (const float*)d_in[0];
    const float* feat_s   = (const float*)d_in[1];
    const float* weight_a = (const float*)d_in[2];

    char* ws = (char*)d_ws;
    float* ssqp = (float*)ws;                                  // 4 B
    short* WT   = (short*)(ws + 512);                          // 512 KB
    short* Hp   = (short*)(ws + 512 + 524288);                 // 8 MB
    short* Hs   = (short*)(ws + 512 + 524288 + 8388608);       // 8 MB
    short* FsT  = (short*)(ws + 512 + 524288 + 16777216);      // 8 MB [DIM][NROWS]

    transpose_cast_kernel<<<dim3(DIM / 32, DIM / 32), 256, 0, stream>>>(weight_a, WT, DIM, DIM);
    transpose_cast_kernel<<<dim3(NROWS / 32, DIM / 32), 256, 0, stream>>>(feat_s, FsT, NROWS, DIM);

    gemm1_kernel<<<dim3(NROWS / 128, 2, 2), 512, 0, stream>>>(
        feat_p, feat_s, WT, Hp, Hs);

    hipMemsetAsync(d_out, 0, (size_t)out_size * sizeof(float), stream);
    hipMemsetAsync(ssqp, 0, sizeof(float), stream);

    fused_kernel<<<dim3(NROWS / 64, JSPLIT), 512, 0, stream>>>(Hp, Hs, FsT, (float*)d_out, ssqp);

    scale_kernel<<<(out_size / 4 + 255) / 256, 256, 0, stream>>>((float*)d_out, ssqp);
}